// Round 1
// baseline (435.549 us; speedup 1.0000x reference)
//
#include <hip/hip_runtime.h>
#include <math.h>

#define NS (16*256*64)   // 262144 samples
#define D 32
#define K 8

// ws float layout
#define WS_ENERGY   0
#define WS_COVDIAG  1
#define WS_SG       8        // 8 floats
#define WS_S1       16       // 256 floats [k*32+d]
#define WS_S2       1024     // 8192 floats [k*1024 + d*32 + e]
#define WS_MU       9216     // 256
#define WS_COEF     9472     // 8
#define WS_AINV     16384    // 8192
#define WS_ZERO_COUNT 9216   // zero [0, 9216)

__global__ __launch_bounds__(256) void k_zero(float* __restrict__ ws) {
    int i = blockIdx.x * 256 + threadIdx.x;
    if (i < WS_ZERO_COUNT) ws[i] = 0.0f;
}

// ---------------- Pass 1: moments S2 = sum gamma z z^T, S1 = sum gamma z, SG = sum gamma
__global__ __launch_bounds__(256) void k_moments(const float* __restrict__ z,
                                                 const float* __restrict__ g,
                                                 float* __restrict__ ws) {
    __shared__ float zs[64][32];   // 8 KB
    __shared__ float gs[64][8];    // 2 KB
    const int t  = threadIdx.x;
    const int d  = t & 31;
    const int eg = t >> 5;         // 0..7 -> owns e = eg*4 + j

    float acc[K][4];
#pragma unroll
    for (int k = 0; k < K; k++)
#pragma unroll
        for (int j = 0; j < 4; j++) acc[k][j] = 0.0f;
    float accS1 = 0.0f, accSG = 0.0f;

    const int chunks = NS / 64;    // 4096
    for (int c = blockIdx.x; c < chunks; c += gridDim.x) {
        const int base = c * 64;
        __syncthreads();   // protect previous iteration reads
        // stage 64 samples: z chunk (2048 floats = 512 float4), gamma chunk (512 floats = 128 float4)
        const float4* zsrc = (const float4*)(z + (size_t)base * 32);
        float4* zdst = (float4*)(&zs[0][0]);
        zdst[t]       = zsrc[t];
        zdst[t + 256] = zsrc[t + 256];
        if (t < 128) {
            const float4* gsrc = (const float4*)(g + (size_t)base * 8);
            ((float4*)(&gs[0][0]))[t] = gsrc[t];
        }
        __syncthreads();
#pragma unroll 4
        for (int s = 0; s < 64; s++) {
            float  zd = zs[s][d];
            float4 ze = *(const float4*)(&zs[s][eg * 4]);
            float p0 = zd * ze.x, p1 = zd * ze.y, p2 = zd * ze.z, p3 = zd * ze.w;
            float4 ga = *(const float4*)(&gs[s][0]);
            float4 gb = *(const float4*)(&gs[s][4]);
            float gk[8] = {ga.x, ga.y, ga.z, ga.w, gb.x, gb.y, gb.z, gb.w};
#pragma unroll
            for (int k = 0; k < 8; k++) {
                acc[k][0] += gk[k] * p0;
                acc[k][1] += gk[k] * p1;
                acc[k][2] += gk[k] * p2;
                acc[k][3] += gk[k] * p3;
            }
            accS1 += gs[s][eg] * zd;      // S1[eg][d]
            if (d == 0) accSG += gs[s][eg];
        }
    }
    // flush (each thread owns distinct addresses within a block)
#pragma unroll
    for (int k = 0; k < 8; k++)
#pragma unroll
        for (int j = 0; j < 4; j++)
            atomicAdd(&ws[WS_S2 + k * 1024 + d * 32 + (eg * 4 + j)], acc[k][j]);
    atomicAdd(&ws[WS_S1 + eg * 32 + d], accS1);
    if (d == 0) atomicAdd(&ws[WS_SG + eg], accSG);
}

// ---------------- Pass 2 (tiny): cov, cholesky, inverse, coef, cov_diag
__global__ __launch_bounds__(512) void k_prep(float* __restrict__ ws) {
    __shared__ float A[K][32][33];    // cov_k; lower triangle becomes L
    __shared__ float Tm[K][32][33];   // L^-1
    __shared__ float sg[K];
    __shared__ float mu[K][32];
    __shared__ float logdet[K];

    const int t    = threadIdx.x;
    const int w    = t >> 6;          // wave id = component k
    const int lane = t & 63;

    if (t < 8) sg[t] = ws[WS_SG + t];
    __syncthreads();
    if (t < 256) {
        int k = t >> 5, d = t & 31;
        mu[k][d] = ws[WS_S1 + k * 32 + d] / sg[k];
    }
    __syncthreads();
    // cov_k = S2/sg - mu mu^T + (1e-6 + 1e-9) I
    for (int i = t; i < 8192; i += 512) {
        int k = i >> 10, r = (i >> 5) & 31, c = i & 31;
        float v = ws[WS_S2 + i] / sg[k] - mu[k][r] * mu[k][c];
        if (r == c) v += 1.0e-6f + 1.0e-9f;
        A[k][r][c] = v;
    }
    __syncthreads();
    // cov_diag = sum 1/diag(cov_k)  (before chol overwrites)
    if (t < 256) {
        int k = t >> 5, d = t & 31;
        atomicAdd(&ws[WS_COVDIAG], 1.0f / A[k][d][d]);
    }
    // Cholesky: wave w handles matrix k=w; lanes 0..31 = rows
    {
        const int k = w;
        const int i = lane;
        for (int j = 0; j < 32; j++) {
            __syncthreads();
            float Ljj = sqrtf(A[k][j][j]);
            float Lij = 0.0f;
            if (i > j && i < 32) Lij = A[k][i][j] / Ljj;
            __syncthreads();
            if (i == j) A[k][j][j] = Ljj;
            if (i > j && i < 32) A[k][i][j] = Lij;
            __syncthreads();
            if (i > j && i < 32) {
                for (int c = j + 1; c <= i; c++) A[k][i][c] -= Lij * A[k][c][j];
            }
        }
    }
    __syncthreads();
    // logdet_k = sum log diag(L_k)
    if (t < 8) {
        float s = 0.0f;
        for (int j = 0; j < 32; j++) s += logf(A[t][j][j]);
        logdet[t] = s;
    }
    __syncthreads();
    // T = L^-1 : 256 independent columns (k = t>>5, col j = t&31)
    if (t < 256) {
        int k = t >> 5, j = t & 31;
        Tm[k][j][j] = 1.0f / A[k][j][j];
        for (int r = 0; r < j; r++) Tm[k][r][j] = 0.0f;
        for (int r = j + 1; r < 32; r++) {
            float s = 0.0f;
            for (int c = j; c < r; c++) s += A[k][r][c] * Tm[k][c][j];
            Tm[k][r][j] = -s / A[k][r][r];
        }
    }
    __syncthreads();
    // Ainv = T^T T  -> write to ws
    for (int i = t; i < 8192; i += 512) {
        int k = i >> 10, r = (i >> 5) & 31, c = i & 31;
        float s = 0.0f;
        for (int cc = 0; cc < 32; cc++) s += Tm[k][cc][r] * Tm[k][cc][c];
        ws[WS_AINV + i] = s;
    }
    // coef_k = phi_k / sqrt(det_cov_k); det_cov = (2pi)^16 * prod(diag L)
    // -> sqrt(det_cov) = exp(8*log(2pi) + 0.5*logdet)
    if (t < 8) {
        float phi = sg[t] / (float)NS;
        ws[WS_COEF + t] = phi * expf(-(8.0f * logf(6.283185307179586f) + 0.5f * logdet[t]));
    }
    if (t < 256) ws[WS_MU + t] = mu[t >> 5][t & 31];
}

// ---------------- Pass 3: per-sample energy
__global__ __launch_bounds__(256) void k_energy(const float* __restrict__ z,
                                                float* __restrict__ ws) {
    __shared__ float Ainv[K][32][32];   // 32 KB
    __shared__ float muL[K][32];
    __shared__ float coefL[K];
    __shared__ float red[256];
    const int t = threadIdx.x;
    for (int i = t; i < 8192; i += 256) ((float*)Ainv)[i] = ws[WS_AINV + i];
    ((float*)muL)[t & 255] = ws[WS_MU + (t & 255)];
    if (t < 8) coefL[t] = ws[WS_COEF + t];
    __syncthreads();

    const int n = blockIdx.x * 256 + t;
    float zr[32];
    const float4* zp = (const float4*)(z + (size_t)n * 32);
#pragma unroll
    for (int q = 0; q < 8; q++) {
        float4 v = zp[q];
        zr[4*q] = v.x; zr[4*q+1] = v.y; zr[4*q+2] = v.z; zr[4*q+3] = v.w;
    }
    float ssum = 0.0f;
    for (int k = 0; k < 8; k++) {
        float y[32];
#pragma unroll
        for (int e = 0; e < 32; e++) y[e] = zr[e] - muL[k][e];
        float E = 0.0f;
#pragma unroll
        for (int dd = 0; dd < 32; dd++) {
            const float4* row = (const float4*)(&Ainv[k][dd][0]);
            float v = 0.0f;
#pragma unroll
            for (int q = 0; q < 8; q++) {
                float4 a = row[q];
                v += a.x * y[4*q] + a.y * y[4*q+1] + a.z * y[4*q+2] + a.w * y[4*q+3];
            }
            E += v * y[dd];
        }
        ssum += coefL[k] * expf(-0.5f * E);
    }
    float En = -logf(ssum + 1.0e-6f);
    red[t] = En;
    __syncthreads();
    for (int s2 = 128; s2 > 0; s2 >>= 1) {
        if (t < s2) red[t] += red[t + s2];
        __syncthreads();
    }
    if (t == 0) atomicAdd(&ws[WS_ENERGY], red[0]);
}

__global__ void k_final(const float* __restrict__ ws, float* __restrict__ out) {
    float se = ws[WS_ENERGY] / (float)NS;
    if (!isfinite(se)) se = 0.0f;
    float cd = ws[WS_COVDIAG];
    if (!isfinite(cd)) cd = 0.0f;
    out[0] = 0.1f * se + 0.005f * cd;
}

extern "C" void kernel_launch(void* const* d_in, const int* in_sizes, int n_in,
                              void* d_out, int out_size, void* d_ws, size_t ws_size,
                              hipStream_t stream) {
    const float* z = (const float*)d_in[0];
    const float* g = (const float*)d_in[1];
    float* out = (float*)d_out;
    float* ws  = (float*)d_ws;

    k_zero<<<(WS_ZERO_COUNT + 255) / 256, 256, 0, stream>>>(ws);
    k_moments<<<512, 256, 0, stream>>>(z, g, ws);
    k_prep<<<1, 512, 0, stream>>>(ws);
    k_energy<<<NS / 256, 256, 0, stream>>>(z, ws);
    k_final<<<1, 1, 0, stream>>>(ws, out);
}

// Round 2
// 239.396 us; speedup vs baseline: 1.8194x; 1.8194x over previous
//
#include <hip/hip_runtime.h>
#include <math.h>

#define NS (16*256*64)   // 262144 samples
#define D 32
#define K 8

typedef __attribute__((ext_vector_type(8))) short bf16x8;
typedef __attribute__((ext_vector_type(16))) float f32x16;

// ws float layout
#define WS_ENERGY   0
#define WS_COVDIAG  1
#define WS_C        16     // 8 floats: mu^T Ainv mu per k
#define WS_COEF     24     // 8 floats: phi_k / sqrt(det(2pi cov))
#define WS_SG       32     // 8
#define WS_S1       64     // 256  [k*32+d]
#define WS_S2       1024   // 8192 [k*1024 + r*32 + c]
#define WS_FRAGA    9216   // 4096 floats = 16 frags x 64 lanes x 16B (Ainv bf16 A-operand frags)
#define WS_FRAGB    13312  // 512 floats  = 2 frags  x 64 lanes x 16B (b-rows stacked, A-operand)
#define WS_PART     16384
#define PART_STRIDE 8456   // 8192 S2 + 256 S1 + 8 SG

__device__ __forceinline__ short f2bf(float f) {
    union { float f; unsigned u; } v; v.f = f;
    unsigned r = v.u + 0x7FFFu + ((v.u >> 16) & 1u);   // RNE
    return (short)(r >> 16);
}

// ---------------- Pass 1: moments via MFMA. grid nblk x 256 (4 waves; wave w owns k-pair {2w,2w+1})
__global__ __launch_bounds__(256) void k_moments(const float* __restrict__ z,
                                                 const float* __restrict__ g,
                                                 float* __restrict__ part) {
    const int t   = threadIdx.x;
    const int w   = t >> 6;
    const int l   = t & 63;
    const int col = l & 31;   // d for A-frag, e for B-frag
    const int nh  = l >> 5;   // which 8-sample half of the 16-sample chunk
    const int k0  = 2 * w;

    f32x16 acc0 = {}; f32x16 acc1 = {};
    float s1a = 0.f, s1b = 0.f, sga = 0.f, sgb = 0.f;

    for (int c = blockIdx.x; c < NS / 16; c += gridDim.x) {
        const int nbase = c * 16 + nh * 8;
        float zf[8], ga[8], gb[8];
#pragma unroll
        for (int j = 0; j < 8; j++) {
            zf[j] = z[(size_t)(nbase + j) * 32 + col];
            float2 gg = *(const float2*)(g + (size_t)(nbase + j) * 8 + k0);
            ga[j] = gg.x; gb[j] = gg.y;
        }
        bf16x8 af, b0, b1;
#pragma unroll
        for (int j = 0; j < 8; j++) {
            af[j] = f2bf(zf[j]);
            b0[j] = f2bf(ga[j] * zf[j]);
            b1[j] = f2bf(gb[j] * zf[j]);
        }
        acc0 = __builtin_amdgcn_mfma_f32_32x32x16_bf16(af, b0, acc0, 0, 0, 0);
        acc1 = __builtin_amdgcn_mfma_f32_32x32x16_bf16(af, b1, acc1, 0, 0, 0);
#pragma unroll
        for (int j = 0; j < 8; j++) {
            s1a += ga[j] * zf[j];  s1b += gb[j] * zf[j];
            sga += ga[j];          sgb += gb[j];
        }
    }
    s1a += __shfl_xor(s1a, 32);  s1b += __shfl_xor(s1b, 32);
    sga += __shfl_xor(sga, 32);  sgb += __shfl_xor(sgb, 32);

    float* pb = part + (size_t)blockIdx.x * PART_STRIDE;
#pragma unroll
    for (int r = 0; r < 16; r++) {
        int row = (r & 3) + 8 * (r >> 2) + 4 * nh;   // HW-verified C/D mapping (m74/m101)
        pb[(size_t)k0 * 1024 + row * 32 + col]       = acc0[r];
        pb[(size_t)(k0 + 1) * 1024 + row * 32 + col] = acc1[r];
    }
    if (l < 32) {
        pb[8192 + k0 * 32 + col]       = s1a;
        pb[8192 + (k0 + 1) * 32 + col] = s1b;
    }
    if (l == 0) { pb[8448 + k0] = sga; pb[8448 + k0 + 1] = sgb; }
}

// ---------------- Reduce partials -> ws S2/S1/SG; also zero energy accumulator
__global__ __launch_bounds__(256) void k_reduce(float* __restrict__ ws, int nblk) {
    const int e = blockIdx.x * 256 + threadIdx.x;
    if (e == 0) ws[WS_ENERGY] = 0.0f;
    if (e >= PART_STRIDE) return;
    const float* part = ws + WS_PART;
    float s = 0.f;
    for (int b = 0; b < nblk; b++) s += part[(size_t)b * PART_STRIDE + e];
    if (e < 8192)       ws[WS_S2 + e] = s;
    else if (e < 8448)  ws[WS_S1 + (e - 8192)] = s;
    else                ws[WS_SG + (e - 8448)] = s;
}

// ---------------- Pass 2 (tiny): cov, cov_diag, cholesky, L^-1, Ainv, b, c, coef, bf16 frags
__global__ __launch_bounds__(512) void k_prep(float* __restrict__ ws) {
    __shared__ float A[K][32][33];    // cov -> L -> Ainv
    __shared__ float Tm[K][32][33];   // L^-1
    __shared__ float sg[K];
    __shared__ float mu[K][32];
    __shared__ float bL[K][32];
    __shared__ float red[512];

    const int t    = threadIdx.x;
    const int w    = t >> 6;
    const int lane = t & 63;

    if (t < 8) sg[t] = ws[WS_SG + t];
    __syncthreads();
    if (t < 256) {
        int k = t >> 5, d = t & 31;
        mu[k][d] = ws[WS_S1 + k * 32 + d] / sg[k];
    }
    __syncthreads();
    for (int i = t; i < 8192; i += 512) {
        int k = i >> 10, r = (i >> 5) & 31, c = i & 31;
        float v = ws[WS_S2 + i] / sg[k] - mu[k][r] * mu[k][c];
        if (r == c) v += 1.0e-6f + 1.0e-9f;
        A[k][r][c] = v;
    }
    __syncthreads();
    red[t] = (t < 256) ? 1.0f / A[t >> 5][t & 31][t & 31] : 0.0f;
    __syncthreads();
    for (int s2 = 256; s2 > 0; s2 >>= 1) { if (t < s2) red[t] += red[t + s2]; __syncthreads(); }
    if (t == 0) ws[WS_COVDIAG] = red[0];
    // Cholesky: wave w handles matrix k=w; lanes 0..31 = rows
    {
        const int k = w;
        const int i = lane;
        for (int j = 0; j < 32; j++) {
            __syncthreads();
            float Ljj = sqrtf(A[k][j][j]);
            float Lij = 0.0f;
            if (i > j && i < 32) Lij = A[k][i][j] / Ljj;
            __syncthreads();
            if (i == j) A[k][j][j] = Ljj;
            if (i > j && i < 32) A[k][i][j] = Lij;
            __syncthreads();
            if (i > j && i < 32) {
                for (int c = j + 1; c <= i; c++) A[k][i][c] -= Lij * A[k][c][j];
            }
        }
    }
    __syncthreads();
    if (t < 8) {
        float s = 0.0f;
        for (int j = 0; j < 32; j++) s += logf(A[t][j][j]);
        float phi = sg[t] / (float)NS;
        ws[WS_COEF + t] = phi * expf(-(8.0f * logf(6.283185307179586f) + 0.5f * s));
    }
    __syncthreads();
    if (t < 256) {
        int k = t >> 5, j = t & 31;
        Tm[k][j][j] = 1.0f / A[k][j][j];
        for (int r = 0; r < j; r++) Tm[k][r][j] = 0.0f;
        for (int r = j + 1; r < 32; r++) {
            float s = 0.0f;
            for (int c = j; c < r; c++) s += A[k][r][c] * Tm[k][c][j];
            Tm[k][r][j] = -s / A[k][r][r];
        }
    }
    __syncthreads();
    for (int i = t; i < 8192; i += 512) {
        int k = i >> 10, r = (i >> 5) & 31, c = i & 31;
        float s = 0.0f;
        for (int cc = 0; cc < 32; cc++) s += Tm[k][cc][r] * Tm[k][cc][c];
        A[k][r][c] = s;
    }
    __syncthreads();
    if (t < 256) {
        int k = t >> 5, e = t & 31;
        float s = 0.0f;
        for (int c = 0; c < 32; c++) s += A[k][e][c] * mu[k][c];
        bL[k][e] = s;
    }
    __syncthreads();
    if (t < 8) {
        float s = 0.0f;
        for (int c = 0; c < 32; c++) s += mu[t][c] * bL[t][c];
        ws[WS_C + t] = s;
    }
    {
        int k = w;
        for (int h = 0; h < 2; h++) {
            int r = lane & 31, cb = (lane >> 5) * 8 + 16 * h;
            unsigned uu[4];
#pragma unroll
            for (int q = 0; q < 4; q++) {
                unsigned lo = (unsigned short)f2bf(A[k][r][cb + 2 * q]);
                unsigned hi = (unsigned short)f2bf(A[k][r][cb + 2 * q + 1]);
                uu[q] = lo | (hi << 16);
            }
            ((uint4*)(ws + WS_FRAGA))[(k * 2 + h) * 64 + lane] = make_uint4(uu[0], uu[1], uu[2], uu[3]);
        }
    }
    if (t < 128) {
        int h = t >> 6, l2 = t & 63;
        int r = l2 & 31, cb = (l2 >> 5) * 8 + 16 * h;
        unsigned uu[4];
#pragma unroll
        for (int q = 0; q < 4; q++) {
            float v0 = (r < 8) ? bL[r][cb + 2 * q] : 0.0f;
            float v1 = (r < 8) ? bL[r][cb + 2 * q + 1] : 0.0f;
            uu[q] = (unsigned)(unsigned short)f2bf(v0) | ((unsigned)(unsigned short)f2bf(v1) << 16);
        }
        ((uint4*)(ws + WS_FRAGB))[h * 64 + l2] = make_uint4(uu[0], uu[1], uu[2], uu[3]);
    }
}

// ---------------- Pass 3: energy via MFMA. grid 512 x 512 (8 waves), 2 chunks of 32 samples/wave
__global__ __launch_bounds__(512) void k_energy(const float* __restrict__ z,
                                                float* __restrict__ ws) {
    __shared__ uint4 frg[1152];      // [0,1024): Ainv frags, [1024,1152): b frags
    __shared__ float red[512];
    const int t   = threadIdx.x;
    const int w   = t >> 6;
    const int l   = t & 63;
    const int col = l & 31;
    const int nh  = l >> 5;

    for (int i = t; i < 1152; i += 512) frg[i] = ((const uint4*)(ws + WS_FRAGA))[i];
    float cf[8], cc[8];
#pragma unroll
    for (int k = 0; k < 8; k++) { cf[k] = ws[WS_COEF + k]; cc[k] = ws[WS_C + k]; }
    __syncthreads();

    float En = 0.0f;
    for (int ci = 0; ci < 2; ci++) {
        const int chunk = (blockIdx.x * 8 + w) * 2 + ci;
        const int n0 = chunk * 32;
        const float* zb = z + (size_t)(n0 + col) * 32 + nh * 8;
        float4 a0 = *(const float4*)(zb + 0);
        float4 a1 = *(const float4*)(zb + 4);
        float4 a2 = *(const float4*)(zb + 16);
        float4 a3 = *(const float4*)(zb + 20);
        float zlo[8] = {a0.x,a0.y,a0.z,a0.w,a1.x,a1.y,a1.z,a1.w};
        float zhi[8] = {a2.x,a2.y,a2.z,a2.w,a3.x,a3.y,a3.z,a3.w};
        bf16x8 b0, b1;
#pragma unroll
        for (int j = 0; j < 8; j++) { b0[j] = f2bf(zlo[j]); b1[j] = f2bf(zhi[j]); }
        float olo[4], ohi[4];
#pragma unroll
        for (int j = 0; j < 4; j++) {
            float mlo = nh ? zlo[j] : zlo[j + 4];
            float mhi = nh ? zhi[j] : zhi[j + 4];
            olo[j] = __shfl_xor(mlo, 32);
            ohi[j] = __shfl_xor(mhi, 32);
        }
        float zdot[16];
#pragma unroll
        for (int j = 0; j < 4; j++) {
            zdot[j]      = nh ? olo[j]     : zlo[j];
            zdot[4 + j]  = nh ? zlo[4 + j] : olo[j];
            zdot[8 + j]  = nh ? ohi[j]     : zhi[j];
            zdot[12 + j] = nh ? zhi[4 + j] : ohi[j];
        }
        f32x16 acc2 = {};
        {
            bf16x8 fb0 = *(const bf16x8*)&frg[1024 + l];
            bf16x8 fb1 = *(const bf16x8*)&frg[1024 + 64 + l];
            acc2 = __builtin_amdgcn_mfma_f32_32x32x16_bf16(fb0, b0, acc2, 0, 0, 0);
            acc2 = __builtin_amdgcn_mfma_f32_32x32x16_bf16(fb1, b1, acc2, 0, 0, 0);
        }
        float oth[4];
#pragma unroll
        for (int r = 0; r < 4; r++) oth[r] = __shfl_xor(acc2[r], 32);
        float pk[8];
#pragma unroll
        for (int k = 0; k < 8; k++) {
            bf16x8 fa0 = *(const bf16x8*)&frg[(k * 2 + 0) * 64 + l];
            bf16x8 fa1 = *(const bf16x8*)&frg[(k * 2 + 1) * 64 + l];
            f32x16 acc = {};
            acc = __builtin_amdgcn_mfma_f32_32x32x16_bf16(fa0, b0, acc, 0, 0, 0);
            acc = __builtin_amdgcn_mfma_f32_32x32x16_bf16(fa1, b1, acc, 0, 0, 0);
            float p = 0.0f;
#pragma unroll
            for (int r = 0; r < 16; r++) p += acc[r] * zdot[r];
            p += __shfl_xor(p, 32);
            pk[k] = p;
        }
        float ssum = 0.0f;
#pragma unroll
        for (int k = 0; k < 8; k++) {
            float d2 = (k < 4) ? (nh ? oth[k] : acc2[k]) : (nh ? acc2[k - 4] : oth[k - 4]);
            float E = pk[k] - 2.0f * d2 + cc[k];
            ssum += cf[k] * __expf(-0.5f * E);
        }
        En += -__logf(ssum + 1.0e-6f);
    }
    red[t] = En;
    __syncthreads();
    for (int s2 = 256; s2 > 0; s2 >>= 1) { if (t < s2) red[t] += red[t + s2]; __syncthreads(); }
    if (t == 0) atomicAdd(&ws[WS_ENERGY], red[0]);
}

__global__ void k_final(const float* __restrict__ ws, float* __restrict__ out) {
    float se = ws[WS_ENERGY] * 0.5f / (float)NS;   // each sample counted by 2 lane-halves
    if (!isfinite(se)) se = 0.0f;
    float cd = ws[WS_COVDIAG];
    if (!isfinite(cd)) cd = 0.0f;
    out[0] = 0.1f * se + 0.005f * cd;
}

extern "C" void kernel_launch(void* const* d_in, const int* in_sizes, int n_in,
                              void* d_out, int out_size, void* d_ws, size_t ws_size,
                              hipStream_t stream) {
    const float* z = (const float*)d_in[0];
    const float* g = (const float*)d_in[1];
    float* out = (float*)d_out;
    float* ws  = (float*)d_ws;

    long avail = (long)(ws_size / 4) - WS_PART;
    int nblk = (int)(avail / PART_STRIDE);
    if (nblk > 512) nblk = 512;
    if (nblk < 1)   nblk = 1;

    k_moments<<<nblk, 256, 0, stream>>>(z, g, ws + WS_PART);
    k_reduce<<<(PART_STRIDE + 255) / 256, 256, 0, stream>>>(ws, nblk);
    k_prep<<<1, 512, 0, stream>>>(ws);
    k_energy<<<512, 512, 0, stream>>>(z, ws);
    k_final<<<1, 1, 0, stream>>>(ws, out);
}

// Round 3
// 118.082 us; speedup vs baseline: 3.6885x; 2.0274x over previous
//
#include <hip/hip_runtime.h>
#include <math.h>

#define NS (16*256*64)   // 262144 samples
#define D 32
#define K 8

typedef __attribute__((ext_vector_type(8))) short bf16x8;
typedef __attribute__((ext_vector_type(16))) float f32x16;

// ws float layout
#define WS_ENERGY   0
#define WS_COVDIAG  1
#define WS_C        16     // 8 floats: mu^T Ainv mu per k
#define WS_COEF     24     // 8 floats: phi_k / sqrt(det(2pi cov))
#define WS_SG       32     // 8
#define WS_S1       64     // 256  [k*32+d]
#define WS_S2       1024   // 8192 [k*1024 + r*32 + c]
#define WS_FRAGA    9216   // 4096 floats = 16 frags x 64 lanes x 16B (Ainv bf16 A-operand frags)
#define WS_FRAGB    13312  // 512 floats  = 2 frags  x 64 lanes x 16B (b-rows stacked, A-operand)
#define WS_PART     16384
#define PART_STRIDE 8456   // 8192 S2 + 256 S1 + 8 SG

__device__ __forceinline__ short f2bf(float f) {
    union { float f; unsigned u; } v; v.f = f;
    unsigned r = v.u + 0x7FFFu + ((v.u >> 16) & 1u);   // RNE
    return (short)(r >> 16);
}

// ---------------- Pass 1: moments via MFMA, z/gamma staged in LDS once per block.
// grid nblk x 256 (4 waves; wave w owns k-pair {2w,2w+1})
__global__ __launch_bounds__(256) void k_moments(const float* __restrict__ z,
                                                 const float* __restrict__ g,
                                                 float* __restrict__ part) {
    __shared__ float zs[64][32];   // 8 KB
    __shared__ float gs[64][8];    // 2 KB
    const int t   = threadIdx.x;
    const int w   = t >> 6;
    const int l   = t & 63;
    const int col = l & 31;   // d for A-frag, e for B-frag
    const int nh  = l >> 5;   // which 8-sample half of a 16-sample sub-chunk
    const int k0  = 2 * w;

    f32x16 acc0 = {}; f32x16 acc1 = {};
    float s1a = 0.f, s1b = 0.f, sga = 0.f, sgb = 0.f;

    for (int c = blockIdx.x; c < NS / 64; c += gridDim.x) {
        const int base = c * 64;
        __syncthreads();   // protect previous iteration's LDS reads
        const float4* zsrc = (const float4*)(z + (size_t)base * 32);
        float4* zdst = (float4*)(&zs[0][0]);
        zdst[t]       = zsrc[t];
        zdst[t + 256] = zsrc[t + 256];
        if (t < 128) {
            ((float4*)(&gs[0][0]))[t] = ((const float4*)(g + (size_t)base * 8))[t];
        }
        __syncthreads();
#pragma unroll
        for (int sc = 0; sc < 4; sc++) {
            const int s0 = sc * 16 + nh * 8;
            float zf[8], ga[8], gb[8];
#pragma unroll
            for (int j = 0; j < 8; j++) {
                zf[j] = zs[s0 + j][col];
                float2 gg = *(const float2*)(&gs[s0 + j][k0]);
                ga[j] = gg.x; gb[j] = gg.y;
            }
            bf16x8 af, b0, b1;
#pragma unroll
            for (int j = 0; j < 8; j++) {
                float p0 = ga[j] * zf[j];
                float p1 = gb[j] * zf[j];
                af[j] = f2bf(zf[j]);
                b0[j] = f2bf(p0);
                b1[j] = f2bf(p1);
                s1a += p0;  s1b += p1;
                sga += ga[j];  sgb += gb[j];
            }
            acc0 = __builtin_amdgcn_mfma_f32_32x32x16_bf16(af, b0, acc0, 0, 0, 0);
            acc1 = __builtin_amdgcn_mfma_f32_32x32x16_bf16(af, b1, acc1, 0, 0, 0);
        }
    }
    s1a += __shfl_xor(s1a, 32);  s1b += __shfl_xor(s1b, 32);
    sga += __shfl_xor(sga, 32);  sgb += __shfl_xor(sgb, 32);

    float* pb = part + (size_t)blockIdx.x * PART_STRIDE;
#pragma unroll
    for (int r = 0; r < 16; r++) {
        int row = (r & 3) + 8 * (r >> 2) + 4 * nh;   // HW-verified C/D mapping (m74/m101)
        pb[(size_t)k0 * 1024 + row * 32 + col]       = acc0[r];
        pb[(size_t)(k0 + 1) * 1024 + row * 32 + col] = acc1[r];
    }
    if (l < 32) {
        pb[8192 + k0 * 32 + col]       = s1a;
        pb[8192 + (k0 + 1) * 32 + col] = s1b;
    }
    if (l == 0) { pb[8448 + k0] = sga; pb[8448 + k0 + 1] = sgb; }
}

// ---------------- Reduce partials -> ws S2/S1/SG. Parallel over BOTH axes.
// grid ceil(8456/64) x 1024: el = t&63 (coalesced elems), bg = t>>6 (16 b-groups)
__global__ __launch_bounds__(1024) void k_reduce(float* __restrict__ ws, int nblk) {
    __shared__ float red[16][64];
    const int t  = threadIdx.x;
    const int el = t & 63;
    const int bg = t >> 6;
    const int e  = blockIdx.x * 64 + el;
    const float* part = ws + WS_PART;
    float s = 0.0f;
    if (e < PART_STRIDE) {
        for (int b = bg; b < nblk; b += 16)
            s += part[(size_t)b * PART_STRIDE + e];
    }
    red[bg][el] = s;
    __syncthreads();
#pragma unroll
    for (int h = 8; h > 0; h >>= 1) {
        if (bg < h) red[bg][el] += red[bg + h][el];
        __syncthreads();
    }
    if (bg == 0 && e < PART_STRIDE) {
        float v = red[0][el];
        if (e < 8192)       ws[WS_S2 + e] = v;
        else if (e < 8448)  ws[WS_S1 + (e - 8192)] = v;
        else                ws[WS_SG + (e - 8448)] = v;
    }
    if (blockIdx.x == 0 && t == 0) ws[WS_ENERGY] = 0.0f;
}

// ---------------- Pass 2 (tiny): cov, cov_diag, cholesky, L^-1, Ainv, b, c, coef, bf16 frags
__global__ __launch_bounds__(512) void k_prep(float* __restrict__ ws) {
    __shared__ float A[K][32][33];    // cov -> L -> Ainv
    __shared__ float Tm[K][32][33];   // L^-1
    __shared__ float sg[K];
    __shared__ float mu[K][32];
    __shared__ float bL[K][32];
    __shared__ float red[512];

    const int t    = threadIdx.x;
    const int w    = t >> 6;
    const int lane = t & 63;

    if (t < 8) sg[t] = ws[WS_SG + t];
    __syncthreads();
    if (t < 256) {
        int k = t >> 5, d = t & 31;
        mu[k][d] = ws[WS_S1 + k * 32 + d] / sg[k];
    }
    __syncthreads();
    for (int i = t; i < 8192; i += 512) {
        int k = i >> 10, r = (i >> 5) & 31, c = i & 31;
        float v = ws[WS_S2 + i] / sg[k] - mu[k][r] * mu[k][c];
        if (r == c) v += 1.0e-6f + 1.0e-9f;
        A[k][r][c] = v;
    }
    __syncthreads();
    red[t] = (t < 256) ? 1.0f / A[t >> 5][t & 31][t & 31] : 0.0f;
    __syncthreads();
    for (int s2 = 256; s2 > 0; s2 >>= 1) { if (t < s2) red[t] += red[t + s2]; __syncthreads(); }
    if (t == 0) ws[WS_COVDIAG] = red[0];
    // Cholesky: wave w handles matrix k=w; lanes 0..31 = rows
    {
        const int k = w;
        const int i = lane;
        for (int j = 0; j < 32; j++) {
            __syncthreads();
            float Ljj = sqrtf(A[k][j][j]);
            float Lij = 0.0f;
            if (i > j && i < 32) Lij = A[k][i][j] / Ljj;
            __syncthreads();
            if (i == j) A[k][j][j] = Ljj;
            if (i > j && i < 32) A[k][i][j] = Lij;
            __syncthreads();
            if (i > j && i < 32) {
                for (int c = j + 1; c <= i; c++) A[k][i][c] -= Lij * A[k][c][j];
            }
        }
    }
    __syncthreads();
    if (t < 8) {
        float s = 0.0f;
        for (int j = 0; j < 32; j++) s += logf(A[t][j][j]);
        float phi = sg[t] / (float)NS;
        ws[WS_COEF + t] = phi * expf(-(8.0f * logf(6.283185307179586f) + 0.5f * s));
    }
    __syncthreads();
    if (t < 256) {
        int k = t >> 5, j = t & 31;
        Tm[k][j][j] = 1.0f / A[k][j][j];
        for (int r = 0; r < j; r++) Tm[k][r][j] = 0.0f;
        for (int r = j + 1; r < 32; r++) {
            float s = 0.0f;
            for (int c = j; c < r; c++) s += A[k][r][c] * Tm[k][c][j];
            Tm[k][r][j] = -s / A[k][r][r];
        }
    }
    __syncthreads();
    for (int i = t; i < 8192; i += 512) {
        int k = i >> 10, r = (i >> 5) & 31, c = i & 31;
        float s = 0.0f;
        for (int cc = 0; cc < 32; cc++) s += Tm[k][cc][r] * Tm[k][cc][c];
        A[k][r][c] = s;
    }
    __syncthreads();
    if (t < 256) {
        int k = t >> 5, e = t & 31;
        float s = 0.0f;
        for (int c = 0; c < 32; c++) s += A[k][e][c] * mu[k][c];
        bL[k][e] = s;
    }
    __syncthreads();
    if (t < 8) {
        float s = 0.0f;
        for (int c = 0; c < 32; c++) s += mu[t][c] * bL[t][c];
        ws[WS_C + t] = s;
    }
    {
        int k = w;
        for (int h = 0; h < 2; h++) {
            int r = lane & 31, cb = (lane >> 5) * 8 + 16 * h;
            unsigned uu[4];
#pragma unroll
            for (int q = 0; q < 4; q++) {
                unsigned lo = (unsigned short)f2bf(A[k][r][cb + 2 * q]);
                unsigned hi = (unsigned short)f2bf(A[k][r][cb + 2 * q + 1]);
                uu[q] = lo | (hi << 16);
            }
            ((uint4*)(ws + WS_FRAGA))[(k * 2 + h) * 64 + lane] = make_uint4(uu[0], uu[1], uu[2], uu[3]);
        }
    }
    if (t < 128) {
        int h = t >> 6, l2 = t & 63;
        int r = l2 & 31, cb = (l2 >> 5) * 8 + 16 * h;
        unsigned uu[4];
#pragma unroll
        for (int q = 0; q < 4; q++) {
            float v0 = (r < 8) ? bL[r][cb + 2 * q] : 0.0f;
            float v1 = (r < 8) ? bL[r][cb + 2 * q + 1] : 0.0f;
            uu[q] = (unsigned)(unsigned short)f2bf(v0) | ((unsigned)(unsigned short)f2bf(v1) << 16);
        }
        ((uint4*)(ws + WS_FRAGB))[h * 64 + l2] = make_uint4(uu[0], uu[1], uu[2], uu[3]);
    }
}

// ---------------- Pass 3: energy via MFMA. grid 512 x 512 (8 waves), 2 chunks of 32 samples/wave
__global__ __launch_bounds__(512) void k_energy(const float* __restrict__ z,
                                                float* __restrict__ ws) {
    __shared__ uint4 frg[1152];      // [0,1024): Ainv frags, [1024,1152): b frags
    __shared__ float red[512];
    const int t   = threadIdx.x;
    const int w   = t >> 6;
    const int l   = t & 63;
    const int col = l & 31;
    const int nh  = l >> 5;

    for (int i = t; i < 1152; i += 512) frg[i] = ((const uint4*)(ws + WS_FRAGA))[i];
    float cf[8], cc[8];
#pragma unroll
    for (int k = 0; k < 8; k++) { cf[k] = ws[WS_COEF + k]; cc[k] = ws[WS_C + k]; }
    __syncthreads();

    float En = 0.0f;
    for (int ci = 0; ci < 2; ci++) {
        const int chunk = (blockIdx.x * 8 + w) * 2 + ci;
        const int n0 = chunk * 32;
        const float* zb = z + (size_t)(n0 + col) * 32 + nh * 8;
        float4 a0 = *(const float4*)(zb + 0);
        float4 a1 = *(const float4*)(zb + 4);
        float4 a2 = *(const float4*)(zb + 16);
        float4 a3 = *(const float4*)(zb + 20);
        float zlo[8] = {a0.x,a0.y,a0.z,a0.w,a1.x,a1.y,a1.z,a1.w};
        float zhi[8] = {a2.x,a2.y,a2.z,a2.w,a3.x,a3.y,a3.z,a3.w};
        bf16x8 b0, b1;
#pragma unroll
        for (int j = 0; j < 8; j++) { b0[j] = f2bf(zlo[j]); b1[j] = f2bf(zhi[j]); }
        float olo[4], ohi[4];
#pragma unroll
        for (int j = 0; j < 4; j++) {
            float mlo = nh ? zlo[j] : zlo[j + 4];
            float mhi = nh ? zhi[j] : zhi[j + 4];
            olo[j] = __shfl_xor(mlo, 32);
            ohi[j] = __shfl_xor(mhi, 32);
        }
        float zdot[16];
#pragma unroll
        for (int j = 0; j < 4; j++) {
            zdot[j]      = nh ? olo[j]     : zlo[j];
            zdot[4 + j]  = nh ? zlo[4 + j] : olo[j];
            zdot[8 + j]  = nh ? ohi[j]     : zhi[j];
            zdot[12 + j] = nh ? zhi[4 + j] : ohi[j];
        }
        f32x16 acc2 = {};
        {
            bf16x8 fb0 = *(const bf16x8*)&frg[1024 + l];
            bf16x8 fb1 = *(const bf16x8*)&frg[1024 + 64 + l];
            acc2 = __builtin_amdgcn_mfma_f32_32x32x16_bf16(fb0, b0, acc2, 0, 0, 0);
            acc2 = __builtin_amdgcn_mfma_f32_32x32x16_bf16(fb1, b1, acc2, 0, 0, 0);
        }
        float oth[4];
#pragma unroll
        for (int r = 0; r < 4; r++) oth[r] = __shfl_xor(acc2[r], 32);
        float pk[8];
#pragma unroll
        for (int k = 0; k < 8; k++) {
            bf16x8 fa0 = *(const bf16x8*)&frg[(k * 2 + 0) * 64 + l];
            bf16x8 fa1 = *(const bf16x8*)&frg[(k * 2 + 1) * 64 + l];
            f32x16 acc = {};
            acc = __builtin_amdgcn_mfma_f32_32x32x16_bf16(fa0, b0, acc, 0, 0, 0);
            acc = __builtin_amdgcn_mfma_f32_32x32x16_bf16(fa1, b1, acc, 0, 0, 0);
            float p = 0.0f;
#pragma unroll
            for (int r = 0; r < 16; r++) p += acc[r] * zdot[r];
            p += __shfl_xor(p, 32);
            pk[k] = p;
        }
        float ssum = 0.0f;
#pragma unroll
        for (int k = 0; k < 8; k++) {
            float d2 = (k < 4) ? (nh ? oth[k] : acc2[k]) : (nh ? acc2[k - 4] : oth[k - 4]);
            float E = pk[k] - 2.0f * d2 + cc[k];
            ssum += cf[k] * __expf(-0.5f * E);
        }
        En += -__logf(ssum + 1.0e-6f);
    }
    red[t] = En;
    __syncthreads();
    for (int s2 = 256; s2 > 0; s2 >>= 1) { if (t < s2) red[t] += red[t + s2]; __syncthreads(); }
    if (t == 0) atomicAdd(&ws[WS_ENERGY], red[0]);
}

__global__ void k_final(const float* __restrict__ ws, float* __restrict__ out) {
    float se = ws[WS_ENERGY] * 0.5f / (float)NS;   // each sample counted by 2 lane-halves
    if (!isfinite(se)) se = 0.0f;
    float cd = ws[WS_COVDIAG];
    if (!isfinite(cd)) cd = 0.0f;
    out[0] = 0.1f * se + 0.005f * cd;
}

extern "C" void kernel_launch(void* const* d_in, const int* in_sizes, int n_in,
                              void* d_out, int out_size, void* d_ws, size_t ws_size,
                              hipStream_t stream) {
    const float* z = (const float*)d_in[0];
    const float* g = (const float*)d_in[1];
    float* out = (float*)d_out;
    float* ws  = (float*)d_ws;

    long avail = (long)(ws_size / 4) - WS_PART;
    int nblk = (int)(avail / PART_STRIDE);
    if (nblk > 512) nblk = 512;
    if (nblk < 1)   nblk = 1;

    k_moments<<<nblk, 256, 0, stream>>>(z, g, ws + WS_PART);
    k_reduce<<<(PART_STRIDE + 63) / 64, 1024, 0, stream>>>(ws, nblk);
    k_prep<<<1, 512, 0, stream>>>(ws);
    k_energy<<<512, 512, 0, stream>>>(z, ws);
    k_final<<<1, 1, 0, stream>>>(ws, out);
}

// Round 4
// 104.938 us; speedup vs baseline: 4.1505x; 1.1253x over previous
//
#include <hip/hip_runtime.h>
#include <math.h>

#define NS (16*256*64)   // 262144 samples
#define D 32
#define K 8

typedef __attribute__((ext_vector_type(8))) short bf16x8;
typedef __attribute__((ext_vector_type(16))) float f32x16;

// ws float layout
#define WS_ENERGY   0
#define WS_COVDIAG  1
#define WS_C        16     // 8 floats: mu^T Ainv mu per k
#define WS_COEF     24     // 8 floats: phi_k / sqrt(det(2pi cov))
#define WS_SG       32     // 8
#define WS_S1       64     // 256  [k*32+d]
#define WS_S2       1024   // 8192 [k*1024 + r*32 + c]
#define WS_FRAGA    9216   // 4096 floats = 16 frags x 64 lanes x 16B (Ainv bf16 A-operand frags)
#define WS_FRAGB    13312  // 512 floats  = 2 frags  x 64 lanes x 16B (b-rows stacked, A-operand)
#define WS_PART     16384
#define PART_STRIDE 8456   // 8192 S2 + 256 S1 + 8 SG

__device__ __forceinline__ short f2bf(float f) {
    union { float f; unsigned u; } v; v.f = f;
    unsigned r = v.u + 0x7FFFu + ((v.u >> 16) & 1u);   // RNE
    return (short)(r >> 16);
}

// ---------------- Pass 1: moments via MFMA, z/gamma staged in LDS once per block.
// grid nblk x 256 (4 waves; wave w owns k-pair {2w,2w+1})
__global__ __launch_bounds__(256) void k_moments(const float* __restrict__ z,
                                                 const float* __restrict__ g,
                                                 float* __restrict__ part) {
    __shared__ float zs[64][32];   // 8 KB
    __shared__ float gs[64][8];    // 2 KB
    const int t   = threadIdx.x;
    const int w   = t >> 6;
    const int l   = t & 63;
    const int col = l & 31;   // d for A-frag, e for B-frag
    const int nh  = l >> 5;   // which 8-sample half of a 16-sample sub-chunk
    const int k0  = 2 * w;

    f32x16 acc0 = {}; f32x16 acc1 = {};
    float s1a = 0.f, s1b = 0.f, sga = 0.f, sgb = 0.f;

    for (int c = blockIdx.x; c < NS / 64; c += gridDim.x) {
        const int base = c * 64;
        __syncthreads();   // protect previous iteration's LDS reads
        const float4* zsrc = (const float4*)(z + (size_t)base * 32);
        float4* zdst = (float4*)(&zs[0][0]);
        zdst[t]       = zsrc[t];
        zdst[t + 256] = zsrc[t + 256];
        if (t < 128) {
            ((float4*)(&gs[0][0]))[t] = ((const float4*)(g + (size_t)base * 8))[t];
        }
        __syncthreads();
#pragma unroll
        for (int sc = 0; sc < 4; sc++) {
            const int s0 = sc * 16 + nh * 8;
            float zf[8], ga[8], gb[8];
#pragma unroll
            for (int j = 0; j < 8; j++) {
                zf[j] = zs[s0 + j][col];
                float2 gg = *(const float2*)(&gs[s0 + j][k0]);
                ga[j] = gg.x; gb[j] = gg.y;
            }
            bf16x8 af, b0, b1;
#pragma unroll
            for (int j = 0; j < 8; j++) {
                float p0 = ga[j] * zf[j];
                float p1 = gb[j] * zf[j];
                af[j] = f2bf(zf[j]);
                b0[j] = f2bf(p0);
                b1[j] = f2bf(p1);
                s1a += p0;  s1b += p1;
                sga += ga[j];  sgb += gb[j];
            }
            acc0 = __builtin_amdgcn_mfma_f32_32x32x16_bf16(af, b0, acc0, 0, 0, 0);
            acc1 = __builtin_amdgcn_mfma_f32_32x32x16_bf16(af, b1, acc1, 0, 0, 0);
        }
    }
    s1a += __shfl_xor(s1a, 32);  s1b += __shfl_xor(s1b, 32);
    sga += __shfl_xor(sga, 32);  sgb += __shfl_xor(sgb, 32);

    float* pb = part + (size_t)blockIdx.x * PART_STRIDE;
#pragma unroll
    for (int r = 0; r < 16; r++) {
        int row = (r & 3) + 8 * (r >> 2) + 4 * nh;   // HW-verified C/D mapping (m74/m101)
        pb[(size_t)k0 * 1024 + row * 32 + col]       = acc0[r];
        pb[(size_t)(k0 + 1) * 1024 + row * 32 + col] = acc1[r];
    }
    if (l < 32) {
        pb[8192 + k0 * 32 + col]       = s1a;
        pb[8192 + (k0 + 1) * 32 + col] = s1b;
    }
    if (l == 0) { pb[8448 + k0] = sga; pb[8448 + k0 + 1] = sgb; }
}

// ---------------- Reduce partials -> ws S2/S1/SG. Parallel over BOTH axes.
// Also zeroes the accumulators and the FRAGB region for k_prep/k_energy.
__global__ __launch_bounds__(1024) void k_reduce(float* __restrict__ ws, int nblk) {
    __shared__ float red[16][64];
    const int t  = threadIdx.x;
    const int el = t & 63;
    const int bg = t >> 6;
    const int e  = blockIdx.x * 64 + el;
    const float* part = ws + WS_PART;
    float s = 0.0f;
    if (e < PART_STRIDE) {
        for (int b = bg; b < nblk; b += 16)
            s += part[(size_t)b * PART_STRIDE + e];
    }
    red[bg][el] = s;
    __syncthreads();
#pragma unroll
    for (int h = 8; h > 0; h >>= 1) {
        if (bg < h) red[bg][el] += red[bg + h][el];
        __syncthreads();
    }
    if (bg == 0 && e < PART_STRIDE) {
        float v = red[0][el];
        if (e < 8192)       ws[WS_S2 + e] = v;
        else if (e < 8448)  ws[WS_S1 + (e - 8192)] = v;
        else                ws[WS_SG + (e - 8448)] = v;
    }
    if (blockIdx.x == 0) {
        if (t < 512) ws[WS_FRAGB + t] = 0.0f;   // k_prep fills only rows k<8
        if (t == 0) { ws[WS_ENERGY] = 0.0f; ws[WS_COVDIAG] = 0.0f; }
    }
}

// ---------------- Pass 2: ONE single-wave block PER MATRIX (grid = 8 x 64).
// Single-wave blocks: __syncthreads is cheap, no inter-wave arbitration.
__global__ __launch_bounds__(64) void k_prep(float* __restrict__ ws) {
    __shared__ float A[32][33];    // cov -> L -> Ainv
    __shared__ float Tm[32][33];   // L^-1
    __shared__ float mu[32];
    __shared__ float bL[32];

    const int k   = blockIdx.x;
    const int l   = threadIdx.x;
    const int j32 = l & 31;
    const int ph  = l >> 5;

    const float sgk = ws[WS_SG + k];
    if (l < 32) mu[l] = ws[WS_S1 + k * 32 + l] / sgk;
    __syncthreads();

    // cov_k = S2/sg - mu mu^T + (1e-6 + 1e-9) I
#pragma unroll
    for (int q = 0; q < 16; q++) {
        int idx = q * 64 + l;
        int r = idx >> 5, c = idx & 31;
        float v = ws[WS_S2 + k * 1024 + idx] / sgk - mu[r] * mu[c];
        if (r == c) v += 1.0e-6f + 1.0e-9f;
        A[r][c] = v;
    }
    __syncthreads();

    // cov_diag partial (this matrix): sum 1/diag, one atomic per block
    {
        float tdi = (l < 32) ? 1.0f / A[j32][j32] : 0.0f;
#pragma unroll
        for (int m = 1; m < 32; m <<= 1) tdi += __shfl_xor(tdi, m);
        tdi += __shfl_xor(tdi, 32);
        if (l == 0) atomicAdd(&ws[WS_COVDIAG], tdi);
    }

    // Cholesky, wave-synchronous; lane pairs (i, i+32) split the row update
    for (int j = 0; j < 32; j++) {
        float Ljj = sqrtf(A[j][j]);
        float rL = 1.0f / Ljj;
        if (l == j) A[j][j] = Ljj;
        if (l > j && l < 32) A[l][j] *= rL;
        __syncthreads();
        if (j32 > j) {
            float Lij = A[j32][j];
            for (int c = j + 1 + ph; c <= j32; c += 2)
                A[j32][c] -= Lij * A[c][j];
        }
        __syncthreads();
    }

    // logdet (parallel) + coef
    {
        float ld = (l < 32) ? __logf(A[j32][j32]) : 0.0f;
#pragma unroll
        for (int m = 1; m < 32; m <<= 1) ld += __shfl_xor(ld, m);
        ld += __shfl_xor(ld, 32);
        if (l == 0) {
            float phi = sgk / (float)NS;
            // sqrt(det(2pi*cov)) = exp(16*log(2pi)/2 + 0.5*2*logdet(L)) ; ld = logdet(L)
            ws[WS_COEF + k] = phi * __expf(-(8.0f * 1.8378770664093453f + 0.5f * 2.0f * ld * 0.5f) - 0.5f * ld + 0.5f * ld);
        }
    }
    // NOTE: simplify — coef = phi * exp(-(8*log(2pi) + ld)) ... see corrected line below
    __syncthreads();
    if (l == 0) {
        // det(2pi*cov) = (2pi)^32 * det(cov); sqrt = (2pi)^16 * prod(diagL)
        // reference: det_cov = prod(diag(chol(2pi*cov))) = (2pi)^16 * prod(diagL)
        // coef = phi / det_cov ... wait: reference divides by sqrt(det_cov) where
        // det_cov already = sqrt(det(2pi*cov)); so coef = phi * (2pi)^-8 * prod(diagL)^-0.5
        float ld = 0.0f;
        for (int j = 0; j < 32; j++) ld += __logf(A[j][j]);
        float phi = sgk / (float)NS;
        ws[WS_COEF + k] = phi * __expf(-(8.0f * 1.8378770664093453f + 0.5f * ld));
    }

    // T = L^-1 : lane j (0..31) owns column j
    if (l < 32) {
        const int j = l;
        Tm[j][j] = 1.0f / A[j][j];
        for (int r = 0; r < j; r++) Tm[r][j] = 0.0f;
        for (int r = j + 1; r < 32; r++) {
            float s = 0.0f;
            for (int c = j; c < r; c++) s += A[r][c] * Tm[c][j];
            Tm[r][j] = -s / A[r][r];
        }
    }
    __syncthreads();

    // Ainv = T^T T (triangular bounds: Tm[cc][r] = 0 for cc < r) -> overwrite A
#pragma unroll
    for (int q = 0; q < 16; q++) {
        int idx = q * 64 + l;
        int r = idx >> 5, c = idx & 31;
        int lo = (r > c) ? r : c;
        float s = 0.0f;
        for (int cc = lo; cc < 32; cc++) s += Tm[cc][r] * Tm[cc][c];
        A[r][c] = s;
    }
    __syncthreads();

    // b = Ainv * mu
    if (l < 32) {
        float s = 0.0f;
        for (int c = 0; c < 32; c++) s += A[j32][c] * mu[c];
        bL[j32] = s;
    }
    __syncthreads();
    // c_k = mu . b
    {
        float cm = (l < 32) ? mu[j32] * bL[j32] : 0.0f;
#pragma unroll
        for (int m = 1; m < 32; m <<= 1) cm += __shfl_xor(cm, m);
        cm += __shfl_xor(cm, 32);
        if (l == 0) ws[WS_C + k] = cm;
    }

    // FRAGA: Ainv bf16 A-operand frags for this k
    for (int h = 0; h < 2; h++) {
        int r = j32, cb = ph * 8 + 16 * h;
        unsigned uu[4];
#pragma unroll
        for (int q = 0; q < 4; q++) {
            unsigned lo2 = (unsigned short)f2bf(A[r][cb + 2 * q]);
            unsigned hi2 = (unsigned short)f2bf(A[r][cb + 2 * q + 1]);
            uu[q] = lo2 | (hi2 << 16);
        }
        ((uint4*)(ws + WS_FRAGA))[(k * 2 + h) * 64 + l] = make_uint4(uu[0], uu[1], uu[2], uu[3]);
    }
    // FRAGB: this block fills only its own row (r == k); rest pre-zeroed by k_reduce
    if (j32 == k) {
        for (int h = 0; h < 2; h++) {
            int cb = ph * 8 + 16 * h;
            unsigned uu[4];
#pragma unroll
            for (int q = 0; q < 4; q++) {
                unsigned lo2 = (unsigned short)f2bf(bL[cb + 2 * q]);
                unsigned hi2 = (unsigned short)f2bf(bL[cb + 2 * q + 1]);
                uu[q] = lo2 | (hi2 << 16);
            }
            ((uint4*)(ws + WS_FRAGB))[h * 64 + l] = make_uint4(uu[0], uu[1], uu[2], uu[3]);
        }
    }
}

// ---------------- Pass 3: energy via MFMA. grid 512 x 512 (8 waves), 2 chunks of 32 samples/wave
__global__ __launch_bounds__(512) void k_energy(const float* __restrict__ z,
                                                float* __restrict__ ws) {
    __shared__ uint4 frg[1152];      // [0,1024): Ainv frags, [1024,1152): b frags
    __shared__ float red[512];
    const int t   = threadIdx.x;
    const int w   = t >> 6;
    const int l   = t & 63;
    const int col = l & 31;
    const int nh  = l >> 5;

    for (int i = t; i < 1152; i += 512) frg[i] = ((const uint4*)(ws + WS_FRAGA))[i];
    float cf[8], cc[8];
#pragma unroll
    for (int k = 0; k < 8; k++) { cf[k] = ws[WS_COEF + k]; cc[k] = ws[WS_C + k]; }
    __syncthreads();

    float En = 0.0f;
    for (int ci = 0; ci < 2; ci++) {
        const int chunk = (blockIdx.x * 8 + w) * 2 + ci;
        const int n0 = chunk * 32;
        const float* zb = z + (size_t)(n0 + col) * 32 + nh * 8;
        float4 a0 = *(const float4*)(zb + 0);
        float4 a1 = *(const float4*)(zb + 4);
        float4 a2 = *(const float4*)(zb + 16);
        float4 a3 = *(const float4*)(zb + 20);
        float zlo[8] = {a0.x,a0.y,a0.z,a0.w,a1.x,a1.y,a1.z,a1.w};
        float zhi[8] = {a2.x,a2.y,a2.z,a2.w,a3.x,a3.y,a3.z,a3.w};
        bf16x8 b0, b1;
#pragma unroll
        for (int j = 0; j < 8; j++) { b0[j] = f2bf(zlo[j]); b1[j] = f2bf(zhi[j]); }
        float olo[4], ohi[4];
#pragma unroll
        for (int j = 0; j < 4; j++) {
            float mlo = nh ? zlo[j] : zlo[j + 4];
            float mhi = nh ? zhi[j] : zhi[j + 4];
            olo[j] = __shfl_xor(mlo, 32);
            ohi[j] = __shfl_xor(mhi, 32);
        }
        float zdot[16];
#pragma unroll
        for (int j = 0; j < 4; j++) {
            zdot[j]      = nh ? olo[j]     : zlo[j];
            zdot[4 + j]  = nh ? zlo[4 + j] : olo[j];
            zdot[8 + j]  = nh ? ohi[j]     : zhi[j];
            zdot[12 + j] = nh ? zhi[4 + j] : ohi[j];
        }
        f32x16 acc2 = {};
        {
            bf16x8 fb0 = *(const bf16x8*)&frg[1024 + l];
            bf16x8 fb1 = *(const bf16x8*)&frg[1024 + 64 + l];
            acc2 = __builtin_amdgcn_mfma_f32_32x32x16_bf16(fb0, b0, acc2, 0, 0, 0);
            acc2 = __builtin_amdgcn_mfma_f32_32x32x16_bf16(fb1, b1, acc2, 0, 0, 0);
        }
        float oth[4];
#pragma unroll
        for (int r = 0; r < 4; r++) oth[r] = __shfl_xor(acc2[r], 32);
        float pk[8];
#pragma unroll
        for (int k = 0; k < 8; k++) {
            bf16x8 fa0 = *(const bf16x8*)&frg[(k * 2 + 0) * 64 + l];
            bf16x8 fa1 = *(const bf16x8*)&frg[(k * 2 + 1) * 64 + l];
            f32x16 acc = {};
            acc = __builtin_amdgcn_mfma_f32_32x32x16_bf16(fa0, b0, acc, 0, 0, 0);
            acc = __builtin_amdgcn_mfma_f32_32x32x16_bf16(fa1, b1, acc, 0, 0, 0);
            float p = 0.0f;
#pragma unroll
            for (int r = 0; r < 16; r++) p += acc[r] * zdot[r];
            p += __shfl_xor(p, 32);
            pk[k] = p;
        }
        float ssum = 0.0f;
#pragma unroll
        for (int k = 0; k < 8; k++) {
            float d2 = (k < 4) ? (nh ? oth[k] : acc2[k]) : (nh ? acc2[k - 4] : oth[k - 4]);
            float E = pk[k] - 2.0f * d2 + cc[k];
            ssum += cf[k] * __expf(-0.5f * E);
        }
        En += -__logf(ssum + 1.0e-6f);
    }
    red[t] = En;
    __syncthreads();
    for (int s2 = 256; s2 > 0; s2 >>= 1) { if (t < s2) red[t] += red[t + s2]; __syncthreads(); }
    if (t == 0) atomicAdd(&ws[WS_ENERGY], red[0]);
}

__global__ void k_final(const float* __restrict__ ws, float* __restrict__ out) {
    float se = ws[WS_ENERGY] * 0.5f / (float)NS;   // each sample counted by 2 lane-halves
    if (!isfinite(se)) se = 0.0f;
    float cd = ws[WS_COVDIAG];
    if (!isfinite(cd)) cd = 0.0f;
    out[0] = 0.1f * se + 0.005f * cd;
}

extern "C" void kernel_launch(void* const* d_in, const int* in_sizes, int n_in,
                              void* d_out, int out_size, void* d_ws, size_t ws_size,
                              hipStream_t stream) {
    const float* z = (const float*)d_in[0];
    const float* g = (const float*)d_in[1];
    float* out = (float*)d_out;
    float* ws  = (float*)d_ws;

    long avail = (long)(ws_size / 4) - WS_PART;
    int nblk = (int)(avail / PART_STRIDE);
    if (nblk > 512) nblk = 512;
    if (nblk < 1)   nblk = 1;

    k_moments<<<nblk, 256, 0, stream>>>(z, g, ws + WS_PART);
    k_reduce<<<(PART_STRIDE + 63) / 64, 1024, 0, stream>>>(ws, nblk);
    k_prep<<<8, 64, 0, stream>>>(ws);
    k_energy<<<512, 512, 0, stream>>>(z, ws);
    k_final<<<1, 1, 0, stream>>>(ws, out);
}

// Round 5
// 79.790 us; speedup vs baseline: 5.4587x; 1.3152x over previous
//
#include <hip/hip_runtime.h>
#include <math.h>

#define NS (16*256*64)   // 262144 samples
#define D 32
#define K 8

typedef __attribute__((ext_vector_type(8))) short bf16x8;
typedef __attribute__((ext_vector_type(16))) float f32x16;

// ws float layout
#define WS_ENERGY   0
#define WS_COVDIAG  1
#define WS_C        16     // 8 floats: mu^T Ainv mu per k
#define WS_COEF     24     // 8 floats: phi_k / sqrt(det(2pi cov))
#define WS_SG       32     // 8
#define WS_S1       64     // 256  [k*32+d]
#define WS_S2       1024   // 8192 [k*1024 + r*32 + c]
#define WS_FRAGA    9216   // 4096 floats = 16 frags x 64 lanes x 16B (Ainv bf16 A-operand frags)
#define WS_FRAGB    13312  // 512 floats  = 2 frags  x 64 lanes x 16B (b-rows stacked, A-operand)
#define WS_PART     16384
#define PART_STRIDE 8456   // 8192 S2 + 256 S1 + 8 SG

__device__ __forceinline__ short f2bf(float f) {
    union { float f; unsigned u; } v; v.f = f;
    unsigned r = v.u + 0x7FFFu + ((v.u >> 16) & 1u);   // RNE
    return (short)(r >> 16);
}

// ---------------- Pass 1: moments via MFMA, z/gamma staged in LDS once per block.
// grid nblk x 256 (4 waves; wave w owns k-pair {2w,2w+1})
__global__ __launch_bounds__(256) void k_moments(const float* __restrict__ z,
                                                 const float* __restrict__ g,
                                                 float* __restrict__ part) {
    __shared__ float zs[64][32];   // 8 KB
    __shared__ float gs[64][8];    // 2 KB
    const int t   = threadIdx.x;
    const int w   = t >> 6;
    const int l   = t & 63;
    const int col = l & 31;   // d for A-frag, e for B-frag
    const int nh  = l >> 5;   // which 8-sample half of a 16-sample sub-chunk
    const int k0  = 2 * w;

    f32x16 acc0 = {}; f32x16 acc1 = {};
    float s1a = 0.f, s1b = 0.f, sga = 0.f, sgb = 0.f;

    for (int c = blockIdx.x; c < NS / 64; c += gridDim.x) {
        const int base = c * 64;
        __syncthreads();   // protect previous iteration's LDS reads
        const float4* zsrc = (const float4*)(z + (size_t)base * 32);
        float4* zdst = (float4*)(&zs[0][0]);
        zdst[t]       = zsrc[t];
        zdst[t + 256] = zsrc[t + 256];
        if (t < 128) {
            ((float4*)(&gs[0][0]))[t] = ((const float4*)(g + (size_t)base * 8))[t];
        }
        __syncthreads();
#pragma unroll
        for (int sc = 0; sc < 4; sc++) {
            const int s0 = sc * 16 + nh * 8;
            float zf[8], ga[8], gb[8];
#pragma unroll
            for (int j = 0; j < 8; j++) {
                zf[j] = zs[s0 + j][col];
                float2 gg = *(const float2*)(&gs[s0 + j][k0]);
                ga[j] = gg.x; gb[j] = gg.y;
            }
            bf16x8 af, b0, b1;
#pragma unroll
            for (int j = 0; j < 8; j++) {
                float p0 = ga[j] * zf[j];
                float p1 = gb[j] * zf[j];
                af[j] = f2bf(zf[j]);
                b0[j] = f2bf(p0);
                b1[j] = f2bf(p1);
                s1a += p0;  s1b += p1;
                sga += ga[j];  sgb += gb[j];
            }
            acc0 = __builtin_amdgcn_mfma_f32_32x32x16_bf16(af, b0, acc0, 0, 0, 0);
            acc1 = __builtin_amdgcn_mfma_f32_32x32x16_bf16(af, b1, acc1, 0, 0, 0);
        }
    }
    s1a += __shfl_xor(s1a, 32);  s1b += __shfl_xor(s1b, 32);
    sga += __shfl_xor(sga, 32);  sgb += __shfl_xor(sgb, 32);

    float* pb = part + (size_t)blockIdx.x * PART_STRIDE;
#pragma unroll
    for (int r = 0; r < 16; r++) {
        int row = (r & 3) + 8 * (r >> 2) + 4 * nh;   // HW-verified C/D mapping (m74/m101)
        pb[(size_t)k0 * 1024 + row * 32 + col]       = acc0[r];
        pb[(size_t)(k0 + 1) * 1024 + row * 32 + col] = acc1[r];
    }
    if (l < 32) {
        pb[8192 + k0 * 32 + col]       = s1a;
        pb[8192 + (k0 + 1) * 32 + col] = s1b;
    }
    if (l == 0) { pb[8448 + k0] = sga; pb[8448 + k0 + 1] = sgb; }
}

// ---------------- Reduce partials -> ws S2/S1/SG. Parallel over BOTH axes.
// Also zeroes the accumulators and the FRAGB region for k_prep/k_energy.
__global__ __launch_bounds__(1024) void k_reduce(float* __restrict__ ws, int nblk) {
    __shared__ float red[16][64];
    const int t  = threadIdx.x;
    const int el = t & 63;
    const int bg = t >> 6;
    const int e  = blockIdx.x * 64 + el;
    const float* part = ws + WS_PART;
    float s = 0.0f;
    if (e < PART_STRIDE) {
        for (int b = bg; b < nblk; b += 16)
            s += part[(size_t)b * PART_STRIDE + e];
    }
    red[bg][el] = s;
    __syncthreads();
#pragma unroll
    for (int h = 8; h > 0; h >>= 1) {
        if (bg < h) red[bg][el] += red[bg + h][el];
        __syncthreads();
    }
    if (bg == 0 && e < PART_STRIDE) {
        float v = red[0][el];
        if (e < 8192)       ws[WS_S2 + e] = v;
        else if (e < 8448)  ws[WS_S1 + (e - 8192)] = v;
        else                ws[WS_SG + (e - 8448)] = v;
    }
    if (blockIdx.x == 0) {
        if (t < 512) ws[WS_FRAGB + t] = 0.0f;   // k_prep fills only rows k<8
        if (t == 0) { ws[WS_ENERGY] = 0.0f; ws[WS_COVDIAG] = 0.0f; }
    }
}

// ---------------- Pass 2: one single-wave block per matrix (grid = 8 x 64).
// Fully-unrolled register-resident Gauss-Jordan on [A | I]:
// lane c<32 owns column c of A; lane c>=32 owns column c-32 of I -> becomes Ainv.
// All x[] indices are compile-time (no scratch), elimination uses shfl broadcasts only.
__global__ __launch_bounds__(64) void k_prep(float* __restrict__ ws) {
    __shared__ float Am[32][33];   // Ainv
    __shared__ float mus[32];
    __shared__ float bLs[32];

    const int k   = blockIdx.x;
    const int l   = threadIdx.x;
    const int c32 = l & 31;
    const bool right = l >= 32;

    const float sgk = ws[WS_SG + k];
    if (l < 32) mus[l] = ws[WS_S1 + k * 32 + l] / sgk;
    __syncthreads();
    const float mc  = mus[c32];
    const float rsg = 1.0f / sgk;

    // load cov column (left lanes) / identity column (right lanes) into registers
    float x[32];
    float dval = 1.0f;   // diag(cov) for this lane's column (left lanes)
#pragma unroll
    for (int r = 0; r < 32; r++) {
        float v;
        if (right) {
            v = (r == c32) ? 1.0f : 0.0f;
        } else {
            v = ws[WS_S2 + k * 1024 + r * 32 + c32] * rsg - mus[r] * mc;
            if (r == c32) { v += 1.0e-6f + 1.0e-9f; dval = v; }
        }
        x[r] = v;
    }

    // cov_diag partial: sum 1/diag over left lanes, one atomic per block
    {
        float tdi = right ? 0.0f : 1.0f / dval;
#pragma unroll
        for (int m = 1; m < 64; m <<= 1) tdi += __shfl_xor(tdi, m);
        if (l == 0) atomicAdd(&ws[WS_COVDIAG], tdi);
    }

    // Gauss-Jordan elimination, fully unrolled; logdet from pivots
    float logdet = 0.0f;
#pragma unroll
    for (int j = 0; j < 32; j++) {
        float piv = __shfl(x[j], j);     // A[j][j] current
        float rp  = 1.0f / piv;
        logdet += __logf(piv);
        x[j] *= rp;                      // scale row j across all columns
#pragma unroll
        for (int r = 0; r < 32; r++) {
            if (r == j) continue;
            float m = __shfl(x[r], j);   // A[r][j] from lane j (pre-update for this r)
            x[r] -= m * x[j];
        }
    }
    // right lanes now hold Ainv columns
    if (right) {
#pragma unroll
        for (int r = 0; r < 32; r++) Am[r][c32] = x[r];
    }
    __syncthreads();

    // coef_k = phi * exp(-(8*log(2pi) + 0.25*logdet(cov)))
    // (== R3-verified phi*exp(-(8*log2pi + 0.5*sum(log diag L))) since sum log diag L = 0.5*logdet)
    if (l == 0) {
        float phi = sgk / (float)NS;
        ws[WS_COEF + k] = phi * __expf(-(8.0f * 1.8378770664093453f + 0.25f * logdet));
    }

    // b = Ainv * mu (static-unrolled LDS reads)
    if (l < 32) {
        float s = 0.0f;
#pragma unroll
        for (int c = 0; c < 32; c++) s += Am[c32][c] * mus[c];
        bLs[c32] = s;
    }
    __syncthreads();
    // c_k = mu . b
    {
        float cm = (l < 32) ? mus[c32] * bLs[c32] : 0.0f;
#pragma unroll
        for (int m = 1; m < 64; m <<= 1) cm += __shfl_xor(cm, m);
        if (l == 0) ws[WS_C + k] = cm;
    }

    // FRAGA: Ainv bf16 A-operand frags for this k (lane holds Ainv[row=l&31][(l>>5)*8 + j + 16h])
    {
        const int ph = l >> 5;
#pragma unroll
        for (int h = 0; h < 2; h++) {
            int r = c32, cb = ph * 8 + 16 * h;
            unsigned uu[4];
#pragma unroll
            for (int q = 0; q < 4; q++) {
                unsigned lo2 = (unsigned short)f2bf(Am[r][cb + 2 * q]);
                unsigned hi2 = (unsigned short)f2bf(Am[r][cb + 2 * q + 1]);
                uu[q] = lo2 | (hi2 << 16);
            }
            ((uint4*)(ws + WS_FRAGA))[(k * 2 + h) * 64 + l] = make_uint4(uu[0], uu[1], uu[2], uu[3]);
        }
        // FRAGB: this block fills only its own row (r == k); rest pre-zeroed by k_reduce
        if (c32 == k) {
#pragma unroll
            for (int h = 0; h < 2; h++) {
                int cb = ph * 8 + 16 * h;
                unsigned uu[4];
#pragma unroll
                for (int q = 0; q < 4; q++) {
                    unsigned lo2 = (unsigned short)f2bf(bLs[cb + 2 * q]);
                    unsigned hi2 = (unsigned short)f2bf(bLs[cb + 2 * q + 1]);
                    uu[q] = lo2 | (hi2 << 16);
                }
                ((uint4*)(ws + WS_FRAGB))[h * 64 + l] = make_uint4(uu[0], uu[1], uu[2], uu[3]);
            }
        }
    }
}

// ---------------- Pass 3: energy via MFMA. grid 512 x 512 (8 waves), 2 chunks of 32 samples/wave
__global__ __launch_bounds__(512) void k_energy(const float* __restrict__ z,
                                                float* __restrict__ ws) {
    __shared__ uint4 frg[1152];      // [0,1024): Ainv frags, [1024,1152): b frags
    __shared__ float red[512];
    const int t   = threadIdx.x;
    const int w   = t >> 6;
    const int l   = t & 63;
    const int col = l & 31;
    const int nh  = l >> 5;

    for (int i = t; i < 1152; i += 512) frg[i] = ((const uint4*)(ws + WS_FRAGA))[i];
    float cf[8], cc[8];
#pragma unroll
    for (int k = 0; k < 8; k++) { cf[k] = ws[WS_COEF + k]; cc[k] = ws[WS_C + k]; }
    __syncthreads();

    float En = 0.0f;
    for (int ci = 0; ci < 2; ci++) {
        const int chunk = (blockIdx.x * 8 + w) * 2 + ci;
        const int n0 = chunk * 32;
        const float* zb = z + (size_t)(n0 + col) * 32 + nh * 8;
        float4 a0 = *(const float4*)(zb + 0);
        float4 a1 = *(const float4*)(zb + 4);
        float4 a2 = *(const float4*)(zb + 16);
        float4 a3 = *(const float4*)(zb + 20);
        float zlo[8] = {a0.x,a0.y,a0.z,a0.w,a1.x,a1.y,a1.z,a1.w};
        float zhi[8] = {a2.x,a2.y,a2.z,a2.w,a3.x,a3.y,a3.z,a3.w};
        bf16x8 b0, b1;
#pragma unroll
        for (int j = 0; j < 8; j++) { b0[j] = f2bf(zlo[j]); b1[j] = f2bf(zhi[j]); }
        float olo[4], ohi[4];
#pragma unroll
        for (int j = 0; j < 4; j++) {
            float mlo = nh ? zlo[j] : zlo[j + 4];
            float mhi = nh ? zhi[j] : zhi[j + 4];
            olo[j] = __shfl_xor(mlo, 32);
            ohi[j] = __shfl_xor(mhi, 32);
        }
        float zdot[16];
#pragma unroll
        for (int j = 0; j < 4; j++) {
            zdot[j]      = nh ? olo[j]     : zlo[j];
            zdot[4 + j]  = nh ? zlo[4 + j] : olo[j];
            zdot[8 + j]  = nh ? ohi[j]     : zhi[j];
            zdot[12 + j] = nh ? zhi[4 + j] : ohi[j];
        }
        f32x16 acc2 = {};
        {
            bf16x8 fb0 = *(const bf16x8*)&frg[1024 + l];
            bf16x8 fb1 = *(const bf16x8*)&frg[1024 + 64 + l];
            acc2 = __builtin_amdgcn_mfma_f32_32x32x16_bf16(fb0, b0, acc2, 0, 0, 0);
            acc2 = __builtin_amdgcn_mfma_f32_32x32x16_bf16(fb1, b1, acc2, 0, 0, 0);
        }
        float oth[4];
#pragma unroll
        for (int r = 0; r < 4; r++) oth[r] = __shfl_xor(acc2[r], 32);
        float pk[8];
#pragma unroll
        for (int k = 0; k < 8; k++) {
            bf16x8 fa0 = *(const bf16x8*)&frg[(k * 2 + 0) * 64 + l];
            bf16x8 fa1 = *(const bf16x8*)&frg[(k * 2 + 1) * 64 + l];
            f32x16 acc = {};
            acc = __builtin_amdgcn_mfma_f32_32x32x16_bf16(fa0, b0, acc, 0, 0, 0);
            acc = __builtin_amdgcn_mfma_f32_32x32x16_bf16(fa1, b1, acc, 0, 0, 0);
            float p = 0.0f;
#pragma unroll
            for (int r = 0; r < 16; r++) p += acc[r] * zdot[r];
            p += __shfl_xor(p, 32);
            pk[k] = p;
        }
        float ssum = 0.0f;
#pragma unroll
        for (int k = 0; k < 8; k++) {
            float d2 = (k < 4) ? (nh ? oth[k] : acc2[k]) : (nh ? acc2[k - 4] : oth[k - 4]);
            float E = pk[k] - 2.0f * d2 + cc[k];
            ssum += cf[k] * __expf(-0.5f * E);
        }
        En += -__logf(ssum + 1.0e-6f);
    }
    red[t] = En;
    __syncthreads();
    for (int s2 = 256; s2 > 0; s2 >>= 1) { if (t < s2) red[t] += red[t + s2]; __syncthreads(); }
    if (t == 0) atomicAdd(&ws[WS_ENERGY], red[0]);
}

__global__ void k_final(const float* __restrict__ ws, float* __restrict__ out) {
    float se = ws[WS_ENERGY] * 0.5f / (float)NS;   // each sample counted by 2 lane-halves
    if (!isfinite(se)) se = 0.0f;
    float cd = ws[WS_COVDIAG];
    if (!isfinite(cd)) cd = 0.0f;
    out[0] = 0.1f * se + 0.005f * cd;
}

extern "C" void kernel_launch(void* const* d_in, const int* in_sizes, int n_in,
                              void* d_out, int out_size, void* d_ws, size_t ws_size,
                              hipStream_t stream) {
    const float* z = (const float*)d_in[0];
    const float* g = (const float*)d_in[1];
    float* out = (float*)d_out;
    float* ws  = (float*)d_ws;

    long avail = (long)(ws_size / 4) - WS_PART;
    int nblk = (int)(avail / PART_STRIDE);
    if (nblk > 512) nblk = 512;
    if (nblk < 1)   nblk = 1;

    k_moments<<<nblk, 256, 0, stream>>>(z, g, ws + WS_PART);
    k_reduce<<<(PART_STRIDE + 63) / 64, 1024, 0, stream>>>(ws, nblk);
    k_prep<<<8, 64, 0, stream>>>(ws);
    k_energy<<<512, 512, 0, stream>>>(z, ws);
    k_final<<<1, 1, 0, stream>>>(ws, out);
}